// Round 1
// baseline (462.024 us; speedup 1.0000x reference)
//
#include <hip/hip_runtime.h>
#include <math.h>

namespace {

constexpr int kT = 365;
constexpr int kG = 2000;
constexpr int kM = 8;     // ensemble multiplier
constexpr int kF = 15;    // UH length
constexpr float kPrecs = 1e-5f;

__global__ __launch_bounds__(64, 1) void sacsma_fused(
    const float* __restrict__ x,           // [T, NGRID, 4]
    const float* __restrict__ params_raw,  // [T, NGRID, 11, NMUL]
    const float* __restrict__ conv_params, // [NGRID, 2]
    float* __restrict__ out)               // [T, NGRID]
{
#pragma clang fp contract(off)
    const int tid = blockIdx.x * blockDim.x + threadIdx.x;
    if (tid >= kG * kM) return;
    const int g = tid >> 3;
    const int m = tid & 7;

    // ---- gamma unit-hydrograph weights (identical across the 8 lanes of g) ----
    const float routa = conv_params[2 * g + 0] * 2.9f;
    const float routb = conv_params[2 * g + 1] * 6.5f;
    const float aa    = fmaxf(routa, 0.f) + 0.1f;
    const float theta = fmaxf(routb, 0.f) + 0.5f;
    float w[kF];
    float wsum = 0.f;
#pragma unroll
    for (int k = 0; k < kF; ++k) {
        const float tt = (float)k + 0.5f;
        w[k] = expf(-lgammaf(aa)) * powf(theta, -aa)
             * powf(tt, aa - 1.f) * expf(-tt / theta);
        wsum += w[k];
    }
#pragma unroll
    for (int k = 0; k < kF; ++k) w[k] /= wsum;

    float win[kF];
#pragma unroll
    for (int k = 0; k < kF; ++k) win[k] = 0.f;

    // ---- state init ----
    float uztw = 1e-4f, uzfw = 1e-4f, lztw = 1e-4f, lzfwp = 1e-4f, lzfws = 1e-4f;

    const float* xp = x + (size_t)g * 4;
    const float* pp = params_raw + (size_t)g * 11 * kM + m;

    // software-pipelined prefetch of next timestep's inputs
    float nP = xp[0];
    float nEp = xp[3];
    float npr[11];
#pragma unroll
    for (int i = 0; i < 11; ++i) npr[i] = pp[i * kM];

    for (int t = 0; t < kT; ++t) {
        const float P = nP;
        const float Ep = nEp;
        float pr[11];
#pragma unroll
        for (int i = 0; i < 11; ++i) pr[i] = npr[i];

        if (t + 1 < kT) {
            xp += kG * 4;
            pp += (size_t)kG * 11 * kM;
            nP = xp[0];
            nEp = xp[3];
#pragma unroll
            for (int i = 0; i < 11; ++i) npr[i] = pp[i * kM];
        }

        // ---- scale raw params to physical bounds ----
        const float pctim = pr[0];
        const float smax  = pr[1] * 1999.f + 1.f;
        const float f1    = pr[2] * 0.99f + 0.005f;
        const float f2    = pr[3] * 0.99f + 0.005f;
        const float kuz   = pr[4];
        const float rexp  = pr[5] * 7.f;
        const float f3    = pr[6] * 0.99f + 0.005f;
        const float f4    = pr[7] * 0.99f + 0.005f;
        const float pfree = pr[8];
        const float klzp  = pr[9];
        const float klzs  = pr[10];

        // ---- derived storages ----
        const float uztwm  = fmaxf(kPrecs, f1 * smax);
        const float uzfwm  = fmaxf(kPrecs, f2 * (smax - uztwm));
        const float lztwm  = fmaxf(kPrecs, f3 * (smax - uztwm - uzfwm));
        const float rem    = smax - uztwm - uzfwm - lztwm;
        const float lzfwpm = fmaxf(kPrecs, f4 * rem);
        const float lzfwsm = fmaxf(kPrecs, (1.f - f4) * rem);
        const float pbase  = lzfwpm * klzp + lzfwsm * klzs;
        const float zperc  = (lztwm + lzfwsm * (1.f - klzs)) / pbase
                           + lzfwpm * (1.f - klzp) / pbase;

        // ---- fluxes ----
        const float qdir = pctim * P;
        const float peff = (1.f - pctim) * P;

        const float ru = (uztw / uztwm < uzfw / uzfwm)
            ? (uzfw * uztwm - uztw * uzfwm) / (uztwm + uzfwm) : 0.f;

        const float euztw = fminf(uztw / uztwm * Ep, uztw);             // evap_7, dt=1
        const float twexu = (uztw >= uztwm) ? peff : 0.f;               // saturation_1
        const float qsur  = (uzfw >= uzfwm) ? twexu : 0.f;
        const float qint  = kuz * uzfw;
        const float euzfw = fminf(uzfw, fmaxf(Ep - euztw, 0.f));        // evap_1

        const float deficit = fmaxf(lztwm - lztw, 0.f) + fmaxf(lzfwpm - lzfwp, 0.f)
                            + fmaxf(lzfwsm - lzfws, 0.f);
        const float totalm = lztwm + lzfwpm + lzfwsm;
        const float srel   = fmaxf(1e-8f, uzfw / uzfwm);
        const float demand = pbase * (1.f + zperc * powf(deficit / totalm, 1.f + rexp));
        const float pc     = fmaxf(1e-8f, fminf(uzfw, srel * demand));  // percolation_4

        const float pctw = (1.f - pfree) * pc;
        const float pcfw = pfree * pc;

        const float rd1 = (lzfwpm - lzfwp) / lzfwpm;
        const float rd2 = (lzfwsm - lzfws) / lzfwsm;
        const float trd = rd1 + rd2;
        const float flz = (trd != 0.f) ? rd1 / trd : lzfwpm / (lzfwpm + lzfwsm);

        const float pcfwp = flz * pcfw;
        const float pcfws = (1.f - flz) * pcfw;

        // soilmoisture_2 (both share the same mask condition and S2+S3)
        const float s23m  = lzfwpm + lzfwsm;
        const float lsum  = lzfwp + lzfws;
        const bool  lmask = (lztw / lztwm) < (lsum / s23m);
        const float denA  = s23m * ((lztwm + lzfwpm) + lzfwsm);
        const float denB  = s23m * ((lztwm + lzfwsm) + lzfwpm);
        const float rlp = lmask ? lzfwp * (lztw * s23m + lztwm * lsum) / denA : 0.f;
        const float rls = lmask ? lzfws * (lztw * s23m + lztwm * lsum) / denB : 0.f;

        const float elztw = fminf(lztw / lztwm * fmaxf(Ep - euztw - euzfw, 0.f), lztw);
        const float twexl = (lztw >= lztwm) ? pctw : 0.f;
        const float twexlp = flz * twexl;
        const float twexls = (1.f - flz) * twexl;
        const float qbfp = klzp * lzfwp;
        const float qbfs = klzs * lzfws;

        // ---- state update (clip to [PRECS, max]) ----
        uztw  = fminf(fmaxf(uztw + peff + ru - euztw - twexu, kPrecs), uztwm);
        uzfw  = fminf(fmaxf(uzfw + twexu - ru - euzfw - qint - qsur - pc, kPrecs), uzfwm);
        lztw  = fminf(fmaxf(lztw + pctw - twexl + rlp + rls - elztw, kPrecs), lztwm);
        lzfwp = fminf(fmaxf(lzfwp + pcfwp + twexlp - rlp - qbfp, kPrecs), lzfwpm);
        lzfws = fminf(fmaxf(lzfws + pcfws + twexls - rls - qbfs, kPrecs), lzfwsm);

        float q = qdir + qsur + qint + qbfp + qbfs;

        // ---- ensemble mean across the 8 muls (lanes m=0..7 of the same g) ----
        q += __shfl_xor(q, 1);
        q += __shfl_xor(q, 2);
        q += __shfl_xor(q, 4);
        const float qmean = q * 0.125f;

        // ---- fused causal UH convolution (all lanes redundantly, no divergence) ----
#pragma unroll
        for (int k = kF - 1; k >= 1; --k) win[k] = win[k - 1];
        win[0] = qmean;
        float y = 0.f;
#pragma unroll
        for (int k = 0; k < kF; ++k) y += w[k] * win[k];
        if (m == 0) out[t * kG + g] = y;
    }
}

}  // namespace

extern "C" void kernel_launch(void* const* d_in, const int* in_sizes, int n_in,
                              void* d_out, int out_size, void* d_ws, size_t ws_size,
                              hipStream_t stream) {
    const float* x           = (const float*)d_in[0];
    // d_in[1] = c_hydro_model — unused by the reference forward
    const float* params_raw  = (const float*)d_in[2];
    const float* conv_params = (const float*)d_in[3];
    float* out = (float*)d_out;

    const int total = kG * kM;           // 16000 chains
    const int block = 64;
    const int grid = (total + block - 1) / block;  // 250 blocks
    sacsma_fused<<<grid, block, 0, stream>>>(x, params_raw, conv_params, out);
}

// Round 2
// 261.900 us; speedup vs baseline: 1.7641x; 1.7641x over previous
//
#include <hip/hip_runtime.h>
#include <math.h>

namespace {

constexpr int kT = 365;
constexpr int kG = 2000;
constexpr int kM = 8;     // ensemble multiplier
constexpr int kF = 15;    // UH length
constexpr float kPrecs = 1e-5f;

// param-only derived quantities, computable one pipeline stage ahead
struct Derived {
    float pctim, kuz, pfree, klzp, klzs;
    float uztwm, uzfwm, lztwm, lzfwpm, lzfwsm;
    float r_uztwm, r_uzfwm, r_lztwm, r_lzfwpm, r_lzfwsm, r_uzsum;
    float pbase, zperc, rexp1;
    float r_totalm, s23m, r_s23m, r_den, flz_fb;
};

// fast reciprocal: v_rcp_f32 + one Newton step (~0.5 ulp for normal inputs)
__device__ __forceinline__ float frcp(float x) {
    float r = __builtin_amdgcn_rcpf(x);
    return r * (2.f - x * r);
}

__device__ __forceinline__ Derived make_derived(const float pr[11]) {
#pragma clang fp contract(fast)
    Derived d;
    d.pctim = pr[0];
    const float smax = pr[1] * 1999.f + 1.f;
    const float f1   = pr[2] * 0.99f + 0.005f;
    const float f2   = pr[3] * 0.99f + 0.005f;
    d.kuz            = pr[4];
    const float rexp = pr[5] * 7.f;
    const float f3   = pr[6] * 0.99f + 0.005f;
    const float f4   = pr[7] * 0.99f + 0.005f;
    d.pfree = pr[8]; d.klzp = pr[9]; d.klzs = pr[10];

    d.uztwm  = fmaxf(kPrecs, f1 * smax);
    d.uzfwm  = fmaxf(kPrecs, f2 * (smax - d.uztwm));
    d.lztwm  = fmaxf(kPrecs, f3 * (smax - d.uztwm - d.uzfwm));
    const float rem = smax - d.uztwm - d.uzfwm - d.lztwm;
    d.lzfwpm = fmaxf(kPrecs, f4 * rem);
    d.lzfwsm = fmaxf(kPrecs, (1.f - f4) * rem);

    d.pbase = d.lzfwpm * d.klzp + d.lzfwsm * d.klzs;
    const float r_pbase = frcp(d.pbase);
    d.zperc = (d.lztwm + d.lzfwsm * (1.f - d.klzs)) * r_pbase
            + d.lzfwpm * (1.f - d.klzp) * r_pbase;
    d.rexp1 = 1.f + rexp;

    d.r_uztwm  = frcp(d.uztwm);
    d.r_uzfwm  = frcp(d.uzfwm);
    d.r_lztwm  = frcp(d.lztwm);
    d.r_lzfwpm = frcp(d.lzfwpm);
    d.r_lzfwsm = frcp(d.lzfwsm);
    d.r_uzsum  = frcp(d.uztwm + d.uzfwm);

    const float totalm = d.lztwm + d.lzfwpm + d.lzfwsm;
    d.s23m     = d.lzfwpm + d.lzfwsm;
    d.r_totalm = frcp(totalm);
    d.r_s23m   = frcp(d.s23m);
    d.r_den    = frcp(d.s23m * totalm);   // shared soilmoisture_2 denominator
    d.flz_fb   = d.lzfwpm * d.r_s23m;     // deficit-distribution fallback
    return d;
}

__global__ __launch_bounds__(64, 1) void sacsma_fused(
    const float* __restrict__ x,           // [T, NGRID, 4]
    const float* __restrict__ params_raw,  // [T, NGRID, 11, NMUL]
    const float* __restrict__ conv_params, // [NGRID, 2]
    float* __restrict__ out)               // [T, NGRID]
{
#pragma clang fp contract(fast)
    const int tid = blockIdx.x * blockDim.x + threadIdx.x;
    if (tid >= kG * kM) return;
    const int g = tid >> 3;
    const int m = tid & 7;

    // ---- gamma unit-hydrograph weights (init-only, libm ok) ----
    const float routa = conv_params[2 * g + 0] * 2.9f;
    const float routb = conv_params[2 * g + 1] * 6.5f;
    const float aa    = fmaxf(routa, 0.f) + 0.1f;
    const float theta = fmaxf(routb, 0.f) + 0.5f;
    const float cw    = expf(-lgammaf(aa)) * powf(theta, -aa);
    float w[kF];
    float wsum = 0.f;
#pragma unroll
    for (int k = 0; k < kF; ++k) {
        const float tt = (float)k + 0.5f;
        w[k] = cw * powf(tt, aa - 1.f) * expf(-tt / theta);
        wsum += w[k];
    }
#pragma unroll
    for (int k = 0; k < kF; ++k) w[k] /= wsum;

    float win[kF];
#pragma unroll
    for (int k = 0; k < kF; ++k) win[k] = 0.f;

    // ---- state init ----
    float uztw = 1e-4f, uzfw = 1e-4f, lztw = 1e-4f, lzfwp = 1e-4f, lzfws = 1e-4f;

    const float* xp = x + (size_t)g * 4;
    const float* pp = params_raw + (size_t)g * 11 * kM + m;

    // stage 0: load t=0 params and compute its derived block
    float P = xp[0];
    float Ep = xp[3];
    float pr0[11];
#pragma unroll
    for (int i = 0; i < 11; ++i) pr0[i] = pp[i * kM];
    Derived d = make_derived(pr0);

    float nP = P, nEp = Ep;
    float npr[11];
#pragma unroll
    for (int i = 0; i < 11; ++i) npr[i] = pr0[i];

    for (int t = 0; t < kT; ++t) {
        // issue prefetch for t+1 (consumed at bottom of this iteration)
        if (t + 1 < kT) {
            xp += kG * 4;
            pp += (size_t)kG * 11 * kM;
            nP = xp[0];
            nEp = xp[3];
#pragma unroll
            for (int i = 0; i < 11; ++i) npr[i] = pp[i * kM];
        }

        // ---- fluxes (state-dependent; divides replaced by precomputed recips) ----
        const float qdir = d.pctim * P;
        const float peff = (1.f - d.pctim) * P;

        const float ratio_u1 = uztw * d.r_uztwm;
        const float ratio_u2 = uzfw * d.r_uzfwm;
        const float ru = (ratio_u1 < ratio_u2)
            ? (uzfw * d.uztwm - uztw * d.uzfwm) * d.r_uzsum : 0.f;

        const float euztw = fminf(ratio_u1 * Ep, uztw);
        const float twexu = (uztw >= d.uztwm) ? peff : 0.f;
        const float qsur  = (uzfw >= d.uzfwm) ? twexu : 0.f;
        const float qint  = d.kuz * uzfw;
        const float euzfw = fminf(uzfw, fmaxf(Ep - euztw, 0.f));

        const float deficit = fmaxf(d.lztwm - lztw, 0.f) + fmaxf(d.lzfwpm - lzfwp, 0.f)
                            + fmaxf(d.lzfwsm - lzfws, 0.f);
        const float xrel = deficit * d.r_totalm;
        // pow(x, e) via hw log2/exp2; x==0 -> log2=-inf -> exp2(-inf)=0, matches 0^e
        const float powv = exp2f(d.rexp1 * __log2f(xrel));
        const float demand = d.pbase * (1.f + d.zperc * powv);
        const float srel = fmaxf(1e-8f, ratio_u2);
        const float pc   = fmaxf(1e-8f, fminf(uzfw, srel * demand));

        const float pctw = (1.f - d.pfree) * pc;
        const float pcfw = d.pfree * pc;

        const float rd1 = (d.lzfwpm - lzfwp) * d.r_lzfwpm;
        const float rd2 = (d.lzfwsm - lzfws) * d.r_lzfwsm;
        const float trd = rd1 + rd2;
        const float flz = (trd != 0.f) ? rd1 * frcp(trd) : d.flz_fb;

        const float pcfwp = flz * pcfw;
        const float pcfws = (1.f - flz) * pcfw;

        const float lsum = lzfwp + lzfws;
        const float ratio_l = lztw * d.r_lztwm;
        const bool  lmask = ratio_l < lsum * d.r_s23m;
        const float nume = (lztw * d.s23m + d.lztwm * lsum) * d.r_den;
        const float rlp = lmask ? lzfwp * nume : 0.f;
        const float rls = lmask ? lzfws * nume : 0.f;

        const float elztw = fminf(ratio_l * fmaxf(Ep - euztw - euzfw, 0.f), lztw);
        const float twexl = (lztw >= d.lztwm) ? pctw : 0.f;
        const float twexlp = flz * twexl;
        const float twexls = (1.f - flz) * twexl;
        const float qbfp = d.klzp * lzfwp;
        const float qbfs = d.klzs * lzfws;

        // ---- state update ----
        uztw  = fminf(fmaxf(uztw + peff + ru - euztw - twexu, kPrecs), d.uztwm);
        uzfw  = fminf(fmaxf(uzfw + twexu - ru - euzfw - qint - qsur - pc, kPrecs), d.uzfwm);
        lztw  = fminf(fmaxf(lztw + pctw - twexl + rlp + rls - elztw, kPrecs), d.lztwm);
        lzfwp = fminf(fmaxf(lzfwp + pcfwp + twexlp - rlp - qbfp, kPrecs), d.lzfwpm);
        lzfws = fminf(fmaxf(lzfws + pcfws + twexls - rls - qbfs, kPrecs), d.lzfwsm);

        float q = qdir + qsur + qint + qbfp + qbfs;

        // ---- ensemble mean across the 8 muls (lanes m=0..7 of same g) ----
        q += __shfl_xor(q, 1);
        q += __shfl_xor(q, 2);
        q += __shfl_xor(q, 4);
        const float qmean = q * 0.125f;

        // ---- fused causal UH convolution (redundant on all lanes) ----
#pragma unroll
        for (int k = kF - 1; k >= 1; --k) win[k] = win[k - 1];
        win[0] = qmean;
        float y = 0.f;
#pragma unroll
        for (int k = 0; k < kF; ++k) y += w[k] * win[k];
        if (m == 0) out[t * kG + g] = y;

        // ---- rotate pipeline: derived block for t+1 (param-only, off critical path) ----
        P = nP; Ep = nEp;
        d = make_derived(npr);
    }
}

}  // namespace

extern "C" void kernel_launch(void* const* d_in, const int* in_sizes, int n_in,
                              void* d_out, int out_size, void* d_ws, size_t ws_size,
                              hipStream_t stream) {
    const float* x           = (const float*)d_in[0];
    // d_in[1] = c_hydro_model — unused by the reference forward
    const float* params_raw  = (const float*)d_in[2];
    const float* conv_params = (const float*)d_in[3];
    float* out = (float*)d_out;

    const int total = kG * kM;           // 16000 chains
    const int block = 64;
    const int grid = (total + block - 1) / block;  // 250 waves, ~1/CU
    sacsma_fused<<<grid, block, 0, stream>>>(x, params_raw, conv_params, out);
}

// Round 4
// 177.965 us; speedup vs baseline: 2.5962x; 1.4716x over previous
//
#include <hip/hip_runtime.h>
#include <math.h>

namespace {

constexpr int kT = 365;
constexpr int kG = 2000;
constexpr int kM = 8;     // ensemble multiplier
constexpr int kF = 15;    // UH length
constexpr float kPrecs = 1e-5f;

// ws float offsets: [0, kF*kG) zero pad | q[T][G] | w[15][G]
constexpr int kQBase = kF * kG;
constexpr int kWBase = (kF + kT) * kG;

__device__ __forceinline__ float rcpf(float v) { return __builtin_amdgcn_rcpf(v); }

// v += lane-permuted v via DPP (quad_perm; pure VALU, no LDS)
template <int CTRL>
__device__ __forceinline__ float dpp_xadd(float v) {
    int r = __builtin_amdgcn_update_dpp(0, __float_as_int(v), CTRL, 0xF, 0xF, true);
    return v + __int_as_float(r);
}

// param-only derived quantities (computed one pipeline stage ahead)
struct Derived {
    float pctim, kuz, pfree, klzp, klzs;
    float uztwm, uzfwm, lztwm, lzfwpm, lzfwsm;
    float r_uztwm, r_uzfwm, r_lztwm, r_lzfwpm, r_lzfwsm, r_uzsum;
    float pbase, zperc, rexp1;
    float r_totalm, s23m, r_s23m, r_den, flz_fb;
};

__device__ __forceinline__ Derived make_derived(const float pr[11]) {
#pragma clang fp contract(fast)
    Derived d;
    d.pctim = pr[0];
    const float smax = pr[1] * 1999.f + 1.f;
    const float f1   = pr[2] * 0.99f + 0.005f;
    const float f2   = pr[3] * 0.99f + 0.005f;
    d.kuz            = pr[4];
    const float rexp = pr[5] * 7.f;
    const float f3   = pr[6] * 0.99f + 0.005f;
    const float f4   = pr[7] * 0.99f + 0.005f;
    d.pfree = pr[8]; d.klzp = pr[9]; d.klzs = pr[10];

    d.uztwm  = fmaxf(kPrecs, f1 * smax);
    d.uzfwm  = fmaxf(kPrecs, f2 * (smax - d.uztwm));
    d.lztwm  = fmaxf(kPrecs, f3 * (smax - d.uztwm - d.uzfwm));
    const float rem = smax - d.uztwm - d.uzfwm - d.lztwm;
    d.lzfwpm = fmaxf(kPrecs, f4 * rem);
    d.lzfwsm = fmaxf(kPrecs, (1.f - f4) * rem);

    d.pbase = d.lzfwpm * d.klzp + d.lzfwsm * d.klzs;
    const float r_pbase = rcpf(d.pbase);
    d.zperc = (d.lztwm + d.lzfwsm * (1.f - d.klzs)) * r_pbase
            + d.lzfwpm * (1.f - d.klzp) * r_pbase;
    d.rexp1 = 1.f + rexp;

    d.r_uztwm  = rcpf(d.uztwm);
    d.r_uzfwm  = rcpf(d.uzfwm);
    d.r_lztwm  = rcpf(d.lztwm);
    d.r_lzfwpm = rcpf(d.lzfwpm);
    d.r_lzfwsm = rcpf(d.lzfwsm);
    d.r_uzsum  = rcpf(d.uztwm + d.uzfwm);

    const float totalm = d.lztwm + d.lzfwpm + d.lzfwsm;
    d.s23m     = d.lzfwpm + d.lzfwsm;
    d.r_totalm = rcpf(totalm);
    d.r_s23m   = rcpf(d.s23m);
    d.r_den    = rcpf(d.s23m * totalm);
    d.flz_fb   = d.lzfwpm * d.r_s23m;
    return d;
}

struct PBuf { float pr[11]; float P, Ep; };

// ---------------- kernel A: the sequential scan ----------------
__global__ __launch_bounds__(64, 1) void sacsma_scan(
    const float* __restrict__ x,           // [T, G, 4]
    const float* __restrict__ params_raw,  // [T, G, 11, M]
    float* __restrict__ qs)                // ws q region: [T][G] (sum over m)
{
#pragma clang fp contract(fast)
    const int tid = blockIdx.x * 64 + threadIdx.x;
    const int g = tid >> 3;
    const int m = tid & 7;

    const size_t PS = (size_t)kG * 11 * kM;  // param stride per t
    const size_t XS = (size_t)kG * 4;        // x stride per t
    const float* pp = params_raw + (size_t)g * 11 * kM + m;
    const float* xp = x + (size_t)g * 4;

    float uztw = 1e-4f, uzfw = 1e-4f, lztw = 1e-4f, lzfwp = 1e-4f, lzfws = 1e-4f;

    PBuf A, B;

#define ISSUE(BUF, T3) do {                                          \
        const size_t _po = (size_t)(T3) * PS;                        \
        const size_t _xo = (size_t)(T3) * XS;                        \
        _Pragma("unroll")                                            \
        for (int _i = 0; _i < 11; ++_i) BUF.pr[_i] = pp[_po + _i * kM]; \
        BUF.P = xp[_xo]; BUF.Ep = xp[_xo + 3];                       \
    } while (0)

    // prologue: t=0 params -> derived; prefetch t=1 (A) and t=2 (B)
    ISSUE(A, 0);
    Derived d = make_derived(A.pr);
    float P = A.P, Ep = A.Ep;
    ISSUE(A, 1);
    ISSUE(B, 2);

    float q0 = 0.f, q1 = 0.f, q2 = 0.f, q3 = 0.f;

#define BODY(T, BUF, QREG) do {                                               \
        /* ---- fluxes for step T using d, P, Ep ---- */                      \
        const float qdir = d.pctim * P;                                       \
        const float peff = (1.f - d.pctim) * P;                               \
        const float ratio_u1 = uztw * d.r_uztwm;                              \
        const float ratio_u2 = uzfw * d.r_uzfwm;                              \
        const float ru = (ratio_u1 < ratio_u2)                                \
            ? (uzfw * d.uztwm - uztw * d.uzfwm) * d.r_uzsum : 0.f;            \
        const float euztw = fminf(ratio_u1 * Ep, uztw);                       \
        const float twexu = (uztw >= d.uztwm) ? peff : 0.f;                   \
        const float qsur  = (uzfw >= d.uzfwm) ? twexu : 0.f;                  \
        const float qint  = d.kuz * uzfw;                                     \
        const float euzfw = fminf(uzfw, fmaxf(Ep - euztw, 0.f));              \
        const float deficit = fmaxf(d.lztwm - lztw, 0.f)                      \
            + fmaxf(d.lzfwpm - lzfwp, 0.f) + fmaxf(d.lzfwsm - lzfws, 0.f);    \
        const float xrel = deficit * d.r_totalm;                              \
        const float powv = exp2f(d.rexp1 * __log2f(xrel));                    \
        const float demand = d.pbase * (1.f + d.zperc * powv);                \
        const float srel = fmaxf(1e-8f, ratio_u2);                            \
        const float pc   = fmaxf(1e-8f, fminf(uzfw, srel * demand));          \
        const float pctw = (1.f - d.pfree) * pc;                              \
        const float pcfw = d.pfree * pc;                                      \
        const float rd1 = (d.lzfwpm - lzfwp) * d.r_lzfwpm;                    \
        const float rd2 = (d.lzfwsm - lzfws) * d.r_lzfwsm;                    \
        const float trd = rd1 + rd2;                                          \
        const float flz = (trd != 0.f) ? rd1 * rcpf(trd) : d.flz_fb;          \
        const float pcfwp = flz * pcfw;                                       \
        const float pcfws = (1.f - flz) * pcfw;                               \
        const float lsum = lzfwp + lzfws;                                     \
        const float ratio_l = lztw * d.r_lztwm;                               \
        const bool  lmask = ratio_l < lsum * d.r_s23m;                        \
        const float nume = (lztw * d.s23m + d.lztwm * lsum) * d.r_den;        \
        const float rlp = lmask ? lzfwp * nume : 0.f;                         \
        const float rls = lmask ? lzfws * nume : 0.f;                         \
        const float elztw = fminf(ratio_l * fmaxf(Ep - euztw - euzfw, 0.f), lztw); \
        const float twexl = (lztw >= d.lztwm) ? pctw : 0.f;                   \
        const float twexlp = flz * twexl;                                     \
        const float twexls = (1.f - flz) * twexl;                             \
        const float qbfp = d.klzp * lzfwp;                                    \
        const float qbfs = d.klzs * lzfws;                                    \
        uztw  = fminf(fmaxf(uztw + peff + ru - euztw - twexu, kPrecs), d.uztwm);   \
        uzfw  = fminf(fmaxf(uzfw + twexu - ru - euzfw - qint - qsur - pc, kPrecs), d.uzfwm); \
        lztw  = fminf(fmaxf(lztw + pctw - twexl + rlp + rls - elztw, kPrecs), d.lztwm);      \
        lzfwp = fminf(fmaxf(lzfwp + pcfwp + twexlp - rlp - qbfp, kPrecs), d.lzfwpm);         \
        lzfws = fminf(fmaxf(lzfws + pcfws + twexls - rls - qbfs, kPrecs), d.lzfwsm);         \
        QREG = qdir + qsur + qint + qbfp + qbfs;                              \
        /* ---- rotate pipeline: read BUF (t+1), then reissue BUF <- t+3 ---- */ \
        const float _Pn = BUF.P, _En = BUF.Ep;                                \
        const Derived _dn = make_derived(BUF.pr);                             \
        if ((T) + 3 < kT) ISSUE(BUF, (T) + 3);                                \
        d = _dn; P = _Pn; Ep = _En;                                           \
    } while (0)

    // batched m-reduction + store of 4 steps: xor1/xor2 via DPP, xor4 via swizzle
#define FLUSH(TB) do {                                                        \
        q0 = dpp_xadd<0xB1>(q0); q1 = dpp_xadd<0xB1>(q1);                     \
        q2 = dpp_xadd<0xB1>(q2); q3 = dpp_xadd<0xB1>(q3);                     \
        q0 = dpp_xadd<0x4E>(q0); q1 = dpp_xadd<0x4E>(q1);                     \
        q2 = dpp_xadd<0x4E>(q2); q3 = dpp_xadd<0x4E>(q3);                     \
        q0 += __shfl_xor(q0, 4); q1 += __shfl_xor(q1, 4);                     \
        q2 += __shfl_xor(q2, 4); q3 += __shfl_xor(q3, 4);                     \
        const float _v01 = (m & 1) ? q1 : q0;                                 \
        const float _v23 = (m & 1) ? q3 : q2;                                 \
        const float _v = (m & 2) ? _v23 : _v01;                               \
        if (m < 4) qs[(size_t)((TB) + m) * kG + g] = _v;                      \
    } while (0)

    for (int t = 0; t < 357; t += 4) {   // bodies 0..359, issues <= 362
        BODY(t,     A, q0);
        BODY(t + 1, B, q1);
        BODY(t + 2, A, q2);
        BODY(t + 3, B, q3);
        FLUSH(t);
    }
    // tail: bodies 360..364 (issues guarded by the constant-folded (T)+3<kT)
    BODY(360, A, q0);
    BODY(361, B, q1);
    BODY(362, A, q2);
    BODY(363, B, q3);
    FLUSH(360);
    BODY(364, A, q0);   // A holds stale data; derived result unused
    q0 = dpp_xadd<0xB1>(q0);
    q0 = dpp_xadd<0x4E>(q0);
    q0 += __shfl_xor(q0, 4);
    if (m == 0) qs[(size_t)364 * kG + g] = q0;

#undef BODY
#undef ISSUE
#undef FLUSH
}

// ---------------- kernel B: gamma UH weights (x0.125 ensemble-mean fold) ----------------
__global__ void uh_weights(const float* __restrict__ conv_params,
                           float* __restrict__ wbuf)   // [15][G]
{
    const int g = blockIdx.x * blockDim.x + threadIdx.x;
    if (g >= kG) return;
    const float aa = fmaxf(conv_params[2 * g] * 2.9f, 0.f) + 0.1f;
    const float th = fmaxf(conv_params[2 * g + 1] * 6.5f, 0.f) + 0.5f;
    const float cw = expf(-lgammaf(aa)) * powf(th, -aa);
    float w[kF];
    float s = 0.f;
#pragma unroll
    for (int k = 0; k < kF; ++k) {
        const float tt = (float)k + 0.5f;
        w[k] = cw * powf(tt, aa - 1.f) * expf(-tt / th);
        s += w[k];
    }
    const float inv = 0.125f / s;   // normalize + fold ensemble mean (q stored as sum)
#pragma unroll
    for (int k = 0; k < kF; ++k) wbuf[k * kG + g] = w[k] * inv;
}

// ---------------- kernel C: causal UH convolution ----------------
__global__ void uh_conv(const float* __restrict__ ws,   // base of scratch
                        float* __restrict__ out)        // [T][G]
{
    const int tid = blockIdx.x * blockDim.x + threadIdx.x;
    if (tid >= kT * kG) return;
    const int t = tid / kG;
    const int g = tid - t * kG;
    const float* q = ws + kQBase;   // q[t] at q[t*kG+g]; t<0 hits the zero pad
    const float* w = ws + kWBase;
    float y = 0.f;
#pragma unroll
    for (int k = 0; k < kF; ++k)
        y += w[k * kG + g] * q[(ptrdiff_t)(t - k) * kG + g];
    out[(size_t)t * kG + g] = y;
}

}  // namespace

extern "C" void kernel_launch(void* const* d_in, const int* in_sizes, int n_in,
                              void* d_out, int out_size, void* d_ws, size_t ws_size,
                              hipStream_t stream) {
    const float* x           = (const float*)d_in[0];
    // d_in[1] = c_hydro_model — unused by the reference forward
    const float* params_raw  = (const float*)d_in[2];
    const float* conv_params = (const float*)d_in[3];
    float* out = (float*)d_out;
    float* ws  = (float*)d_ws;

    // zero the q pad region (t<0 taps) — every call, since replays don't re-poison
    (void)hipMemsetAsync(ws, 0, (size_t)kF * kG * sizeof(float), stream);

    uh_weights<<<(kG + 255) / 256, 256, 0, stream>>>(conv_params, ws + kWBase);
    sacsma_scan<<<(kG * kM) / 64, 64, 0, stream>>>(x, params_raw, ws + kQBase);
    uh_conv<<<(kT * kG + 255) / 256, 256, 0, stream>>>(ws, out);
}